// Round 2
// baseline (172.444 us; speedup 1.0000x reference)
//
#include <hip/hip_runtime.h>
#include <hip/hip_bf16.h>

#define T_  30
#define B_  64
#define V_  32
#define F_  128
#define L_  64
#define LF_ 64
#define TH_ 20
#define H_  4
#define HD_ 32

typedef __attribute__((ext_vector_type(8))) short bf16x8;   // 8 bf16 = 4 VGPR
typedef __attribute__((ext_vector_type(4))) float f32x4;
#define MFMA(a,b,c) __builtin_amdgcn_mfma_f32_16x16x32_bf16(a, b, c, 0, 0, 0)

__device__ __forceinline__ float bf1(unsigned short u) {
    unsigned int x = ((unsigned int)u) << 16; float f; __builtin_memcpy(&f, &x, 4); return f;
}
// pack two f32 -> two bf16 (RTNE, v_cvt_pk_bf16_f32); lo half = a, hi half = b
__device__ __forceinline__ unsigned int cvtpk(float a, float b) {
    __hip_bfloat162 h = __float22bfloat162_rn(make_float2(a, b));
    unsigned int r; __builtin_memcpy(&r, &h, 4); return r;
}
// packed 4-element bf16 store (8B, must be 8B-aligned)
__device__ __forceinline__ void st4pk(unsigned short* p, float a, float b, float c, float d) {
    uint2 u = { cvtpk(a, b), cvtpk(c, d) };
    *(uint2*)p = u;
}
// Load one MFMA A/B-fragment (8 bf16) from a weight matrix of either dtype.
__device__ __forceinline__ bf16x8 ldWfrag(const void* W, int off, bool isBf16) {
    if (isBf16) return *(const bf16x8*)((const unsigned short*)W + off);
    const float* p = (const float*)W + off;
    float4 a = *(const float4*)p;
    float4 b = *(const float4*)(p + 4);
    uint4 u = { cvtpk(a.x, a.y), cvtpk(a.z, a.w), cvtpk(b.x, b.y), cvtpk(b.z, b.w) };
    bf16x8 r; __builtin_memcpy(&r, &u, 16); return r;
}

// One block per (b,v). 8 waves: wave w -> head h=w>>1, half s=w&1.
// Projection phases (B/C/E) use SWAPPED operands (A=weights, B=activations) so the
// C-layout gives each lane 4 CONSECUTIVE output columns at one row:
//   every epilogue = 2x v_cvt_pk_bf16_f32 + 1x ds_write_b64 (vs 16 scalar b16 writes),
//   Phase-E output = float4 global stores, residual = float4 loads,
//   PV normalization = 1 v_rcp per lane (ssum indexed by t = lane&15).
// sLanes padded 80->88 ushorts: b128 reads go 4-way -> 2-way (free) bank aliasing.
// 3 barriers, LDS 64512B -> 2 blocks/CU x 8 waves = 16 waves/CU.
__global__ __launch_bounds__(512, 4)
void lane_attn_kernel(const void* __restrict__ veh,    // [T,B,V,F]
                      const void* __restrict__ lanes,  // [B,V,L,LF]
                      const void* __restrict__ maskp,  // [TH,B,V,L] uint8 or int32 (probed)
                      const void* __restrict__ Wk, const void* __restrict__ Wv,
                      const void* __restrict__ Wq, const void* __restrict__ Wc,
                      float* __restrict__ outp)        // [T,B,V,F] fp32
{
    const int bv    = blockIdx.x;
    const int tid   = threadIdx.x;
    const int w     = tid >> 6;
    const int h     = w >> 1;      // head
    const int shalf = w & 1;       // half within head
    const int lane  = tid & 63;
    const int quad  = lane >> 4;
    const int lm    = lane & 15;
    const int fbase = h * 32;
    const int fs    = fbase + shalf * 16;   // wave's 16-col f-slice

    // LDS overlays (ushort units):
    //   sQ    @0     [32][136]  (written C, read scores)
    //   sO    @0     [32][136]  (written PV; row x col disjoint vs live sQ reads)
    //   sLanes@4352  [64][88]   (A..B; pitch 88 = conflict-free b128 reads)
    //   sVehB @9984  [32][136]  (A..C)
    //   sS    @4352  [4][32][72](scores..PV, overlays sLanes+sVehB after barrier 2)
    __shared__ __align__(16) unsigned short sRegion[14336];
    __shared__ __align__(16) unsigned short sK [64 * 136];   // [l][f]
    __shared__ __align__(16) unsigned short sVt[128 * 72];   // [f][l]
    unsigned short* sQ     = sRegion;
    unsigned short* sO     = sRegion;
    unsigned short* sLanes = sRegion + 4352;
    unsigned short* sVehB  = sRegion + 9984;
    unsigned short* sS     = sRegion + 4352;

    // ---------- per-wave probes (wave-uniform, no LDS/barrier) ----------
    const unsigned short* vh16 = (const unsigned short*)veh;
    const int field = (vh16[2 * lane] >> 7) & 0xFF;
    const bool isBf16 = __popcll(__ballot(field >= 100 && field <= 130)) >= 32;
    const unsigned char* mbp = (const unsigned char*)maskp;
    const bool maskByte = (__ballot(mbp[4 * lane + 1] != 0) != 0ULL);

    // ---------- per-lane mask OR over TH (l = lane) -> wave-uniform bitmask ----------
    bool ok;
    {
        const int* mi = (const int*)maskp;
        int o = 0;
        #pragma unroll
        for (int th = 0; th < TH_; ++th) {
            const size_t e = (size_t)th * (B_ * V_ * L_) + (size_t)bv * L_ + lane;
            o |= maskByte ? (int)mbp[e] : mi[e];
        }
        ok = (o != 0);
    }
    const unsigned long long mok = __ballot(ok);   // bit l = mask for lane-row l

    // ---------- preload weight fragments for this wave's 16-row slice ----------
    bf16x8 wbK[2], wbV[2], wq[4];
    #pragma unroll
    for (int kt = 0; kt < 2; ++kt) {
        const int off = (fs + lm) * 64 + kt * 32 + quad * 8;
        wbK[kt] = ldWfrag(Wk, off, isBf16);
        wbV[kt] = ldWfrag(Wv, off, isBf16);
    }
    #pragma unroll
    for (int kt = 0; kt < 4; ++kt)
        wq[kt] = ldWfrag(Wq, (fs + lm) * 128 + kt * 32 + quad * 8, isBf16);

    // ---------- Phase A: stage lanes[64][88] + veh[32][136] as bf16 ----------
    for (int u = tid; u < 64 * 16; u += 512) {
        const int l = u >> 4, c4 = u & 15;
        if (isBf16) {
            ushort4 x = ((const ushort4*)lanes)[bv * (L_ * LF_ / 4) + u];
            *(ushort4*)&sLanes[l * 88 + c4 * 4] = x;
        } else {
            float4 x = ((const float4*)lanes)[bv * (L_ * LF_ / 4) + u];
            uint2 y = { cvtpk(x.x, x.y), cvtpk(x.z, x.w) };
            *(uint2*)&sLanes[l * 88 + c4 * 4] = y;
        }
    }
    for (int u = tid; u < 32 * 32; u += 512) {
        const int t = u >> 5, c4 = u & 31;
        uint2 y = { 0, 0 };
        if (t < T_) {
            const int idx = (t * (B_ * V_) + bv) * (F_ / 4) + c4;
            if (isBf16) {
                ushort4 x = ((const ushort4*)veh)[idx];
                __builtin_memcpy(&y, &x, 8);
            } else {
                float4 x = ((const float4*)veh)[idx];
                y.x = cvtpk(x.x, x.y); y.y = cvtpk(x.z, x.w);
            }
        }
        *(uint2*)&sVehB[t * 136 + c4 * 4] = y;
    }
    __syncthreads();   // barrier 1: staging visible to all waves

    // ---------- Phase B: K/V projection for rows [fs, fs+16) ----------
    // K swapped (A=Wk, B=lanes): lane holds K[f = fs+quad*4+r][l = mt*16+lm] -> sK[l][f] packed.
    // V unswapped (A=lanes, B=Wv): lane holds V[l = mt*16+quad*4+r][f = fs+lm] -> sVt[f][l] packed.
    {
        f32x4 accK[4], accV[4];
        #pragma unroll
        for (int mt = 0; mt < 4; ++mt) { accK[mt] = (f32x4)0.f; accV[mt] = (f32x4)0.f; }
        #pragma unroll
        for (int kt = 0; kt < 2; ++kt) {
            bf16x8 a[4];
            #pragma unroll
            for (int mt = 0; mt < 4; ++mt)
                a[mt] = *(const bf16x8*)&sLanes[(mt * 16 + lm) * 88 + kt * 32 + quad * 8];
            #pragma unroll
            for (int mt = 0; mt < 4; ++mt) {
                accK[mt] = MFMA(wbK[kt], a[mt], accK[mt]);   // C[f][l]
                accV[mt] = MFMA(a[mt], wbV[kt], accV[mt]);   // C[l][f]
            }
        }
        #pragma unroll
        for (int mt = 0; mt < 4; ++mt) {
            st4pk(&sK[(mt * 16 + lm) * 136 + fs + quad * 4],
                  accK[mt][0], accK[mt][1], accK[mt][2], accK[mt][3]);
            st4pk(&sVt[(fs + lm) * 72 + mt * 16 + quad * 4],
                  accV[mt][0], accV[mt][1], accV[mt][2], accV[mt][3]);
        }
    }

    // ---------- Phase C: Q projection (swapped: A=Wq, B=veh), pre-scaled ----------
    // lane holds Q[g = fs+quad*4+r][t = nt*16+lm] -> sQ[t][g] packed.
    {
        f32x4 acc[2];
        acc[0] = (f32x4)0.f; acc[1] = (f32x4)0.f;
        #pragma unroll
        for (int kt = 0; kt < 4; ++kt) {
            bf16x8 b[2];
            #pragma unroll
            for (int nt = 0; nt < 2; ++nt)
                b[nt] = *(const bf16x8*)&sVehB[(nt * 16 + lm) * 136 + kt * 32 + quad * 8];
            #pragma unroll
            for (int nt = 0; nt < 2; ++nt) acc[nt] = MFMA(wq[kt], b[nt], acc[nt]);
        }
        const float sc = 0.17677669529663687f;   // 1/sqrt(32)
        #pragma unroll
        for (int nt = 0; nt < 2; ++nt)
            st4pk(&sQ[(nt * 16 + lm) * 136 + fs + quad * 4],
                  acc[nt][0] * sc, acc[nt][1] * sc, acc[nt][2] * sc, acc[nt][3] * sc);
    }

    // preload E fragments now (consumed after barrier 3; latency hidden)
    bf16x8 wc[4];
    #pragma unroll
    for (int kt = 0; kt < 4; ++kt)
        wc[kt] = ldWfrag(Wc, (fs + lm) * 128 + kt * 32 + quad * 8, isBf16);

    __syncthreads();   // barrier 2: sK/sQ/sVt visible; sLanes/sVehB dead -> sS overlay ok

    // ---------- Scores + fused exp/mask: wave owns t in [16s,16s+16), all l ----------
    // C[l][t]: col = t = lm, rows l = mt*16+quad*4+r -> packed sS[t-row][l] stores.
    {
        bf16x8 a[4], b;
        #pragma unroll
        for (int mt = 0; mt < 4; ++mt)
            a[mt] = *(const bf16x8*)&sK[(mt * 16 + lm) * 136 + fbase + quad * 8];
        b = *(const bf16x8*)&sQ[(shalf * 16 + lm) * 136 + fbase + quad * 8];
        const int t = shalf * 16 + lm;
        const bool tok = (t < T_);
        const unsigned long long msh = (tok ? mok : 0ULL) >> (quad * 4);
        const unsigned int mlo = (unsigned int)msh, mhi = (unsigned int)(msh >> 32);
        #pragma unroll
        for (int mt = 0; mt < 4; ++mt) {
            f32x4 acc = MFMA(a[mt], b, (f32x4)0.f);
            const unsigned int mw = (mt >= 2) ? mhi : mlo;
            const int bp = (mt * 16) & 31;          // compile-time per mt
            float e0 = ((mw >> (bp + 0)) & 1u) ? __expf(acc[0]) : 0.f;
            float e1 = ((mw >> (bp + 1)) & 1u) ? __expf(acc[1]) : 0.f;
            float e2 = ((mw >> (bp + 2)) & 1u) ? __expf(acc[2]) : 0.f;
            float e3 = ((mw >> (bp + 3)) & 1u) ? __expf(acc[3]) : 0.f;
            uint2 y = { cvtpk(e0, e1), cvtpk(e2, e3) };
            *(uint2*)&sS[(h * 32 + t) * 72 + mt * 16 + quad * 4] = y;
        }
    }

    // ---------- PV (swapped: A=Vt, B=P) + ones-MFMA row sums ----------
    // C[f][t]: col = t = lm, rows f = fbase+mt*16+quad*4+r -> packed sO[t][f] stores.
    // ssum = MFMA(ones, P): every row r holds rowsum(P[t=lm]) -> ONE rcp per lane.
    {
        bf16x8 bones;
        #pragma unroll
        for (int j = 0; j < 8; ++j) bones[j] = (short)0x3F80;   // 1.0bf
        f32x4 acc[2], ssum;
        acc[0] = (f32x4)0.f; acc[1] = (f32x4)0.f; ssum = (f32x4)0.f;
        #pragma unroll
        for (int kt = 0; kt < 2; ++kt) {
            bf16x8 bp = *(const bf16x8*)&sS[(h * 32 + shalf * 16 + lm) * 72 + kt * 32 + quad * 8];
            bf16x8 av[2];
            #pragma unroll
            for (int mt = 0; mt < 2; ++mt)
                av[mt] = *(const bf16x8*)&sVt[(fbase + mt * 16 + lm) * 72 + kt * 32 + quad * 8];
            ssum = MFMA(bones, bp, ssum);
            #pragma unroll
            for (int mt = 0; mt < 2; ++mt) acc[mt] = MFMA(av[mt], bp, acc[mt]);
        }
        const float sv  = ssum[0];
        const float inv = (sv > 0.f) ? 1.f / sv : 0.f;   // pad/masked rows -> exact 0
        const int t = shalf * 16 + lm;
        #pragma unroll
        for (int mt = 0; mt < 2; ++mt)
            st4pk(&sO[t * 136 + fbase + mt * 16 + quad * 4],
                  acc[mt][0] * inv, acc[mt][1] * inv, acc[mt][2] * inv, acc[mt][3] * inv);
    }

    // ---------- residual preload: float4/ushort4 (t = nt*16+lm, g = fs+quad*4..+3) ----------
    float4 res[2];
    #pragma unroll
    for (int nt = 0; nt < 2; ++nt) {
        const int t = nt * 16 + lm;
        res[nt] = make_float4(0.f, 0.f, 0.f, 0.f);
        if (t < T_) {
            const size_t off = ((size_t)t * (B_ * V_) + bv) * F_ + fs + quad * 4;
            if (isBf16) {
                ushort4 u = *(const ushort4*)((const unsigned short*)veh + off);
                res[nt] = make_float4(bf1(u.x), bf1(u.y), bf1(u.z), bf1(u.w));
            } else {
                res[nt] = *(const float4*)((const float*)veh + off);
            }
        }
    }
    __syncthreads();   // barrier 3: sO complete across waves

    // ---------- Phase E (swapped: A=Wc, B=O): out = O @ Wc^T + veh ----------
    // C[g][t]: col = t = nt*16+lm, rows g = fs+quad*4+r -> float4 global stores.
    {
        f32x4 acc[2];
        acc[0] = (f32x4)0.f; acc[1] = (f32x4)0.f;
        #pragma unroll
        for (int kt = 0; kt < 4; ++kt) {
            bf16x8 b[2];
            #pragma unroll
            for (int nt = 0; nt < 2; ++nt)
                b[nt] = *(const bf16x8*)&sO[(nt * 16 + lm) * 136 + kt * 32 + quad * 8];
            #pragma unroll
            for (int nt = 0; nt < 2; ++nt) acc[nt] = MFMA(wc[kt], b[nt], acc[nt]);
        }
        #pragma unroll
        for (int nt = 0; nt < 2; ++nt) {
            const int t = nt * 16 + lm;
            if (t < T_) {
                const size_t off = ((size_t)t * (B_ * V_) + bv) * F_ + fs + quad * 4;
                float4 o = make_float4(acc[nt][0] + res[nt].x, acc[nt][1] + res[nt].y,
                                       acc[nt][2] + res[nt].z, acc[nt][3] + res[nt].w);
                *(float4*)&outp[off] = o;
            }
        }
    }
}

extern "C" void kernel_launch(void* const* d_in, const int* in_sizes, int n_in,
                              void* d_out, int out_size, void* d_ws, size_t ws_size,
                              hipStream_t stream) {
    (void)in_sizes; (void)n_in; (void)out_size; (void)d_ws; (void)ws_size;
    lane_attn_kernel<<<dim3(B_ * V_), dim3(512), 0, stream>>>(
        d_in[0], d_in[1], d_in[2], d_in[3], d_in[4], d_in[5], d_in[6],
        (float*)d_out);
}